// Round 1
// baseline (256.190 us; speedup 1.0000x reference)
//
#include <hip/hip_runtime.h>

#define GRID    64
#define BATCH   768
#define C       16
#define NT      30
#define N_KILL  49152
#define N_TRAIL 393216
#define KS      13
#define PAD     6
#define CELLS   (GRID * GRID)   // 4096
#define IMG     (C * CELLS)     // 65536
#define SCALE   234.375f        // 15000 / 64

// Tower grid coords: clip((int)(TOWERS/SCALE), 0, 63), matching numpy f32 math.
__device__ __constant__ int d_tx[NT] = {38,41,47,49,55,53,24,21,15,13, 9, 7,18, 4,33, 6, 4, 5,44,48,48,59,44,56,58,29,58,18,14,58};
__device__ __constant__ int d_ty[NT] = {36,43,47,49,53,55,27,20,15,13, 7, 9,59,44,57,28,18,15,58,58,58,19, 4,35,45, 6,48, 5, 5,48};

// obj markers: DRAG (x=42,y=21), BARON (x=21,y=42)
#define DRAG_X  42
#define DRAG_Y  21
#define BARON_X 21
#define BARON_Y 42

// ---------------------------------------------------------------------------
// Kernel 1: per-batch fill of all 16 channels (ch0..3 computed, ch4..15 zero)
// ---------------------------------------------------------------------------
__global__ __launch_bounds__(256) void fill_kernel(
    const float* __restrict__ dead_mask,   // [B,30]
    const float* __restrict__ obj_status,  // [B,2]
    float* __restrict__ out)               // [B,C,64,64]
{
    const int b   = blockIdx.x;
    const int tid = threadIdx.x;

    __shared__ float s_alive[NT];
    __shared__ float s_obj[2];
    if (tid < NT) s_alive[tid] = (dead_mask[b * NT + tid] > 0.5f) ? 0.0f : 1.0f;
    if (tid < 2)  s_obj[tid]  = obj_status[b * 2 + tid];
    __syncthreads();

    float* base = out + (size_t)b * IMG;

    #pragma unroll
    for (int k = 0; k < CELLS / 256; ++k) {
        const int p = k * 256 + tid;
        const int y = p >> 6;
        const int x = p & 63;

        float c0 = 0.0f, c1 = 0.0f, c2 = 0.0f;
        #pragma unroll
        for (int t = 0; t < NT; ++t) {
            const int dx = x - d_tx[t];
            const int dy = y - d_ty[t];
            const float alive = s_alive[t];
            if (dx == 0 && dy == 0) {
                c0 = fmaxf(c0, alive);
                c1 = fmaxf(c1, 1.0f - alive);
            }
            if (dx * dx + dy * dy <= 16 && alive > 0.0f) c2 = 1.0f;
        }

        float c3 = 0.0f;
        if (y == DRAG_Y  && x == DRAG_X)  c3 = (s_obj[0] > 0.5f) ? 1.0f : 0.0f;
        if (y == BARON_Y && x == BARON_X) c3 = (s_obj[1] > 0.5f) ? 1.0f : 0.0f;

        base[0 * CELLS + p] = c0;
        base[1 * CELLS + p] = c1;
        base[2 * CELLS + p] = c2;
        base[3 * CELLS + p] = c3;
        #pragma unroll
        for (int c = 4; c < C; ++c) base[c * CELLS + p] = 0.0f;
    }
}

// ---------------------------------------------------------------------------
// Kernel 2: scatter-add kills (ch 4+team) and players (ch 6+channel)
// ---------------------------------------------------------------------------
__global__ __launch_bounds__(256) void scatter_kernel(
    const float* __restrict__ kill_coords,  // [N_KILL,2]
    const float* __restrict__ kill_vals,    // [N_KILL]
    const int*   __restrict__ kill_teams,   // [N_KILL]
    const int*   __restrict__ kill_b,       // [N_KILL]
    const float* __restrict__ pl_coords,    // [N_TRAIL,2]
    const float* __restrict__ pl_vals,      // [N_TRAIL]
    const int*   __restrict__ pl_b,         // [N_TRAIL]
    const int*   __restrict__ pl_ch,        // [N_TRAIL]
    float* __restrict__ out)
{
    const int gid = blockIdx.x * 256 + threadIdx.x;
    if (gid < N_KILL) {
        const int   i  = gid;
        const float fx = kill_coords[2 * i];
        const float fy = kill_coords[2 * i + 1];
        const int gx = min(max((int)(fx / SCALE), 0), GRID - 1);
        const int gy = min(max((int)(fy / SCALE), 0), GRID - 1);
        const int b  = kill_b[i];
        const int ch = 4 + kill_teams[i];
        atomicAdd(out + (size_t)b * IMG + ch * CELLS + gy * GRID + gx, kill_vals[i]);
    } else {
        const int   i  = gid - N_KILL;   // < N_TRAIL
        const float fx = pl_coords[2 * i];
        const float fy = pl_coords[2 * i + 1];
        const int gx = min(max((int)(fx / SCALE), 0), GRID - 1);
        const int gy = min(max((int)(fy / SCALE), 0), GRID - 1);
        const int b  = pl_b[i];
        const int ch = 6 + pl_ch[i];
        atomicAdd(out + (size_t)b * IMG + ch * CELLS + gy * GRID + gx, pl_vals[i]);
    }
}

// ---------------------------------------------------------------------------
// Kernel 3: in-place separable 13-tap Gaussian blur, one block per (b,c) image
// ---------------------------------------------------------------------------
__global__ __launch_bounds__(256) void blur_kernel(float* __restrict__ out)
{
    __shared__ float s_in [CELLS];
    __shared__ float s_tmp[CELLS];

    const int tid = threadIdx.x;
    const size_t base = (size_t)blockIdx.x * CELLS;

    // normalized 1D Gaussian weights (sigma=1.5, 13 taps)
    float w[KS];
    {
        float s = 0.0f;
        #pragma unroll
        for (int i = 0; i < KS; ++i) {
            const float d = (float)(i - PAD);
            w[i] = expf(-d * d / 4.5f);   // 2*sigma^2 = 4.5
            s += w[i];
        }
        #pragma unroll
        for (int i = 0; i < KS; ++i) w[i] /= s;
    }

    #pragma unroll
    for (int k = 0; k < CELLS / 256; ++k)
        s_in[k * 256 + tid] = out[base + k * 256 + tid];
    __syncthreads();

    // horizontal pass
    #pragma unroll
    for (int k = 0; k < CELLS / 256; ++k) {
        const int p = k * 256 + tid;
        const int y = p >> 6;
        const int x = p & 63;
        float acc = 0.0f;
        #pragma unroll
        for (int d = -PAD; d <= PAD; ++d) {
            const int xx = x + d;
            if (xx >= 0 && xx < GRID) acc = fmaf(w[d + PAD], s_in[(y << 6) + xx], acc);
        }
        s_tmp[p] = acc;
    }
    __syncthreads();

    // vertical pass, write back in place
    #pragma unroll
    for (int k = 0; k < CELLS / 256; ++k) {
        const int p = k * 256 + tid;
        const int y = p >> 6;
        const int x = p & 63;
        float acc = 0.0f;
        #pragma unroll
        for (int d = -PAD; d <= PAD; ++d) {
            const int yy = y + d;
            if (yy >= 0 && yy < GRID) acc = fmaf(w[d + PAD], s_tmp[(yy << 6) + x], acc);
        }
        out[base + p] = acc;
    }
}

// ---------------------------------------------------------------------------
extern "C" void kernel_launch(void* const* d_in, const int* in_sizes, int n_in,
                              void* d_out, int out_size, void* d_ws, size_t ws_size,
                              hipStream_t stream)
{
    const float* player_coords = (const float*)d_in[0];
    const float* player_vals   = (const float*)d_in[1];
    const float* dead_mask     = (const float*)d_in[2];
    const float* kill_coords   = (const float*)d_in[3];
    const float* kill_vals     = (const float*)d_in[4];
    const float* obj_status    = (const float*)d_in[5];
    const int*   player_b      = (const int*)d_in[6];
    const int*   player_ch     = (const int*)d_in[7];
    const int*   kill_teams    = (const int*)d_in[8];
    const int*   kill_b        = (const int*)d_in[9];
    float* out = (float*)d_out;

    fill_kernel<<<BATCH, 256, 0, stream>>>(dead_mask, obj_status, out);

    const int n_scatter = N_KILL + N_TRAIL;           // 442368
    scatter_kernel<<<n_scatter / 256, 256, 0, stream>>>(
        kill_coords, kill_vals, kill_teams, kill_b,
        player_coords, player_vals, player_b, player_ch, out);

    blur_kernel<<<BATCH * C, 256, 0, stream>>>(out);
}

// Round 2
// 91.743 us; speedup vs baseline: 2.7925x; 2.7925x over previous
//
#include <hip/hip_runtime.h>

#define GRID    64
#define BATCH   768
#define C       16
#define NT      30
#define N_KILL  49152
#define N_TRAIL 393216
#define CELLS   4096
#define IMG     (C * CELLS)
#define SCALE   234.375f
#define NBIN    (BATCH * 12)      // 9216 scatter-channel bins
#define STRIDE  65                // LDS row stride (conflict-free, odd)

// Tower grid coords: clip((int)(TOWERS/SCALE), 0, 63)  (compile-time constants
// so register indices stay static in the unrolled loops)
__device__ constexpr int TX[NT] = {38,41,47,49,55,53,24,21,15,13, 9, 7,18, 4,33, 6, 4, 5,44,48,48,59,44,56,58,29,58,18,14,58};
__device__ constexpr int TY[NT] = {36,43,47,49,53,55,27,20,15,13, 7, 9,59,44,57,28,18,15,58,58,58,19, 4,35,45, 6,48, 5, 5,48};

// ---------------------------------------------------------------------------
// zero the per-bin counters (ws is poisoned, not re-zeroed, by the harness)
// ---------------------------------------------------------------------------
__global__ __launch_bounds__(256) void zero_counts(unsigned* __restrict__ counts) {
    const int gid = blockIdx.x * 256 + threadIdx.x;
    if (gid < NBIN) counts[gid] = 0;
}

// ---------------------------------------------------------------------------
// bin all scatter points by (batch, channel-4).  record = {cell, val}
// ---------------------------------------------------------------------------
__global__ __launch_bounds__(256) void bin_points(
    const float* __restrict__ kc, const float* __restrict__ kv,
    const int*   __restrict__ kt, const int*   __restrict__ kb,
    const float* __restrict__ pc, const float* __restrict__ pv,
    const int*   __restrict__ pb, const int*   __restrict__ pch,
    unsigned* __restrict__ counts, uint2* __restrict__ recs, int cap)
{
    const int gid = blockIdx.x * 256 + threadIdx.x;   // grid sized exactly
    int bin, cell; float val;
    if (gid < N_KILL) {
        const int i = gid;
        const int gx = min(max((int)(kc[2*i]   / SCALE), 0), GRID - 1);
        const int gy = min(max((int)(kc[2*i+1] / SCALE), 0), GRID - 1);
        cell = gy * GRID + gx;
        val  = kv[i];
        bin  = kb[i] * 12 + kt[i];             // ch 4..5
    } else {
        const int i = gid - N_KILL;
        const int gx = min(max((int)(pc[2*i]   / SCALE), 0), GRID - 1);
        const int gy = min(max((int)(pc[2*i+1] / SCALE), 0), GRID - 1);
        cell = gy * GRID + gx;
        val  = pv[i];
        bin  = pb[i] * 12 + 2 + pch[i];        // ch 6..15
    }
    const unsigned slot = atomicAdd(&counts[bin], 1u);
    if (slot < (unsigned)cap)
        recs[(size_t)bin * cap + slot] = make_uint2((unsigned)cell, __float_as_uint(val));
}

// ---------------------------------------------------------------------------
// fallback helpers (only used if ws is too small for the bin table)
// ---------------------------------------------------------------------------
__global__ __launch_bounds__(256) void zero12(float* __restrict__ out) {
    // one block per scatter-channel image
    const int j = blockIdx.x;                 // 0..NBIN-1
    const int b = j / 12, ch = 4 + j % 12;
    float4* p = (float4*)(out + (size_t)(b * C + ch) * CELLS);
    #pragma unroll
    for (int k = 0; k < 4; ++k) p[k * 256 + threadIdx.x] = make_float4(0.f,0.f,0.f,0.f);
}

__global__ __launch_bounds__(256) void scatter_global(
    const float* __restrict__ kc, const float* __restrict__ kv,
    const int*   __restrict__ kt, const int*   __restrict__ kb,
    const float* __restrict__ pc, const float* __restrict__ pv,
    const int*   __restrict__ pb, const int*   __restrict__ pch,
    float* __restrict__ out)
{
    const int gid = blockIdx.x * 256 + threadIdx.x;
    if (gid < N_KILL) {
        const int i = gid;
        const int gx = min(max((int)(kc[2*i]   / SCALE), 0), GRID - 1);
        const int gy = min(max((int)(kc[2*i+1] / SCALE), 0), GRID - 1);
        atomicAdd(out + (size_t)kb[i]*IMG + (4+kt[i])*CELLS + gy*GRID + gx, kv[i]);
    } else {
        const int i = gid - N_KILL;
        const int gx = min(max((int)(pc[2*i]   / SCALE), 0), GRID - 1);
        const int gy = min(max((int)(pc[2*i+1] / SCALE), 0), GRID - 1);
        atomicAdd(out + (size_t)pb[i]*IMG + (6+pch[i])*CELLS + gy*GRID + gx, pv[i]);
    }
}

// ---------------------------------------------------------------------------
// fused build + separable 13-tap blur.  One wave (64 threads) per (b,c) image.
// Thread t = row t for the H-pass (registers), then column t for the V-pass.
// LDS: one 64x65 buffer used only for the transpose (stride 65 -> conflict-free).
// ---------------------------------------------------------------------------
template<bool BINS>
__global__ __launch_bounds__(64) void fused_blur(
    const float* __restrict__ dead_mask,
    const float* __restrict__ obj_status,
    const unsigned* __restrict__ counts,
    const uint2* __restrict__ recs, int cap,
    const float* __restrict__ canvas,       // used when !BINS (aliases out)
    float* __restrict__ out)
{
    const int t  = threadIdx.x;             // 0..63
    const int bc = blockIdx.x;
    const int b  = bc >> 4;
    const int c  = bc & 15;
    const size_t base = (size_t)bc * CELLS;

    __shared__ __align__(16) float s_buf[GRID * STRIDE];
    __shared__ float s_alive[NT];

    if (t < NT) s_alive[t] = (dead_mask[b * NT + t] > 0.5f) ? 0.0f : 1.0f;
    __syncthreads();

    // normalized 13-tap Gaussian (sigma = 1.5)
    float w[13];
    {
        float s = 0.0f;
        #pragma unroll
        for (int i = 0; i < 13; ++i) {
            const float d = (float)(i - 6);
            w[i] = expf(-d * d / 4.5f);
            s += w[i];
        }
        const float inv = 1.0f / s;
        #pragma unroll
        for (int i = 0; i < 13; ++i) w[i] *= inv;
    }

    // ---- build row t of the input image into registers (zero-padded) ----
    float r[76];
    #pragma unroll
    for (int i = 0; i < 76; ++i) r[i] = 0.0f;

    if (c >= 4) {
        if (BINS) {
            // zero the LDS image
            float4 z = make_float4(0.f, 0.f, 0.f, 0.f);
            #pragma unroll
            for (int i = 0; i < 17; ++i) {
                const int idx = i * 64 + t;                 // float4 index
                if (idx < (GRID * STRIDE) / 4) ((float4*)s_buf)[idx] = z;
            }
            __syncthreads();
            const int bin = b * 12 + (c - 4);
            const int n = min((int)counts[bin], cap);
            for (int i = t; i < n; i += 64) {
                const uint2 rec = recs[(size_t)bin * cap + i];
                atomicAdd(&s_buf[(rec.x >> 6) * STRIDE + (rec.x & 63)],
                          __uint_as_float(rec.y));
            }
            __syncthreads();
            #pragma unroll
            for (int k = 0; k < GRID; ++k) r[6 + k] = s_buf[t * STRIDE + k];
        } else {
            #pragma unroll
            for (int k = 0; k < 16; ++k) {
                const float4 v = ((const float4*)(canvas + base))[t * 16 + k];
                r[6 + 4*k + 0] = v.x; r[6 + 4*k + 1] = v.y;
                r[6 + 4*k + 2] = v.z; r[6 + 4*k + 3] = v.w;
            }
        }
    } else if (c == 0) {
        #pragma unroll
        for (int i = 0; i < NT; ++i)
            if (TY[i] == t) r[6 + TX[i]] = fmaxf(r[6 + TX[i]], s_alive[i]);
    } else if (c == 1) {
        #pragma unroll
        for (int i = 0; i < NT; ++i)
            if (TY[i] == t) r[6 + TX[i]] = fmaxf(r[6 + TX[i]], 1.0f - s_alive[i]);
    } else if (c == 2) {
        // union of alive-tower discs, one 64-bit mask per row
        unsigned long long mask = 0ULL;
        #pragma unroll
        for (int i = 0; i < NT; ++i) {
            const int dy  = t - TY[i];
            const int ady = dy < 0 ? -dy : dy;
            if (ady <= 4 && s_alive[i] > 0.0f) {
                const int hw = (ady == 0) ? 4 : (ady <= 2) ? 3 : (ady == 3) ? 2 : 0;
                int lo = TX[i] - hw; if (lo < 0)  lo = 0;
                int hi = TX[i] + hw; if (hi > 63) hi = 63;
                mask |= (((1ULL << (hi - lo + 1)) - 1ULL) << lo);
            }
        }
        #pragma unroll
        for (int x = 0; x < GRID; ++x) r[6 + x] = (float)((mask >> x) & 1ULL);
    } else { // c == 3
        const float o0 = obj_status[b * 2 + 0];
        const float o1 = obj_status[b * 2 + 1];
        if (t == 21) r[6 + 42] = (o0 > 0.5f) ? 1.0f : 0.0f;  // dragon
        if (t == 42) r[6 + 21] = (o1 > 0.5f) ? 1.0f : 0.0f;  // baron
    }

    __syncthreads();   // all s_buf input reads complete before transpose writes

    // ---- H-pass: 13-tap FIR on registers, write transposed to LDS ----
    #pragma unroll
    for (int x = 0; x < GRID; ++x) {
        float acc = 0.0f;
        #pragma unroll
        for (int d = 0; d < 13; ++d) acc = fmaf(w[d], r[x + d], acc);
        s_buf[x * STRIDE + t] = acc;       // s_buf[x][t] = h[row t][col x]
    }
    __syncthreads();

    // ---- V-pass: thread t = output column t ----
    float r2[76];
    #pragma unroll
    for (int i = 0; i < 76; ++i) r2[i] = 0.0f;
    #pragma unroll
    for (int k = 0; k < GRID; ++k) r2[6 + k] = s_buf[t * STRIDE + k];

    #pragma unroll
    for (int y = 0; y < GRID; ++y) {
        float acc = 0.0f;
        #pragma unroll
        for (int d = 0; d < 13; ++d) acc = fmaf(w[d], r2[y + d], acc);
        out[base + y * GRID + t] = acc;    // lanes contiguous in x -> coalesced
    }
}

// ---------------------------------------------------------------------------
extern "C" void kernel_launch(void* const* d_in, const int* in_sizes, int n_in,
                              void* d_out, int out_size, void* d_ws, size_t ws_size,
                              hipStream_t stream)
{
    const float* player_coords = (const float*)d_in[0];
    const float* player_vals   = (const float*)d_in[1];
    const float* dead_mask     = (const float*)d_in[2];
    const float* kill_coords   = (const float*)d_in[3];
    const float* kill_vals     = (const float*)d_in[4];
    const float* obj_status    = (const float*)d_in[5];
    const int*   player_b      = (const int*)d_in[6];
    const int*   player_ch     = (const int*)d_in[7];
    const int*   kill_teams    = (const int*)d_in[8];
    const int*   kill_b        = (const int*)d_in[9];
    float* out = (float*)d_out;

    const size_t counts_bytes = (size_t)NBIN * sizeof(unsigned);
    size_t cap = 0;
    if (ws_size > counts_bytes)
        cap = (ws_size - counts_bytes) / ((size_t)NBIN * sizeof(uint2));
    if (cap > 256) cap = 256;

    const int n_scatter_blocks = (N_KILL + N_TRAIL) / 256;   // 1728

    if (cap >= 128) {
        // primary path: bin points in ws, fused build+blur
        unsigned* counts = (unsigned*)d_ws;
        uint2*    recs   = (uint2*)((char*)d_ws + counts_bytes);
        zero_counts<<<(NBIN + 255) / 256, 256, 0, stream>>>(counts);
        bin_points<<<n_scatter_blocks, 256, 0, stream>>>(
            kill_coords, kill_vals, kill_teams, kill_b,
            player_coords, player_vals, player_b, player_ch,
            counts, recs, (int)cap);
        fused_blur<true><<<BATCH * C, 64, 0, stream>>>(
            dead_mask, obj_status, counts, recs, (int)cap, nullptr, out);
    } else {
        // fallback: scatter through the output canvas
        zero12<<<NBIN, 256, 0, stream>>>(out);
        scatter_global<<<n_scatter_blocks, 256, 0, stream>>>(
            kill_coords, kill_vals, kill_teams, kill_b,
            player_coords, player_vals, player_b, player_ch, out);
        fused_blur<false><<<BATCH * C, 64, 0, stream>>>(
            dead_mask, obj_status, nullptr, nullptr, 0, out, out);
    }
}